// Round 1
// baseline (632.785 us; speedup 1.0000x reference)
//
#include <hip/hip_runtime.h>
#include <hip/hip_bf16.h>

// Problem constants
#define Mdim 2048
#define Ndim 8192
#define Kdim 8192
#define BM 128
#define BN 128
#define BK 64

typedef __bf16 bf16x8 __attribute__((ext_vector_type(8)));
typedef float f32x4 __attribute__((ext_vector_type(4)));
typedef unsigned short ushort8 __attribute__((ext_vector_type(8)));

__device__ __forceinline__ unsigned short f2bf_rne(float f) {
    unsigned u = __float_as_uint(f);
    u += 0x7fffu + ((u >> 16) & 1u);
    return (unsigned short)(u >> 16);
}

// ---------------------------------------------------------------------------
// Kernel 1: dequantize packed 3-bit indices -> bf16 W (Ndim x Kdim, K-major)
// One thread per group of 8 weights (3 packed "bytes" stored as 3 int32s).
// group g: flat weights [8g, 8g+8), codebook block = g/16 (128 weights/block).
// ---------------------------------------------------------------------------
__global__ __launch_bounds__(256) void k_dequant(const int* __restrict__ packed,
                                                 const float* __restrict__ cb,
                                                 unsigned short* __restrict__ W) {
    int g = blockIdx.x * 256 + threadIdx.x;           // 0 .. 8388607
    int p0 = packed[3 * g + 0];
    int p1 = packed[3 * g + 1];
    int p2 = packed[3 * g + 2];
    unsigned bits = (unsigned)(p0 & 255) | ((unsigned)(p1 & 255) << 8) |
                    ((unsigned)(p2 & 255) << 16);
    const float4* cv = (const float4*)(cb + ((size_t)(g >> 4) << 3));
    float4 c0 = cv[0];
    float4 c1 = cv[1];
    ushort8 o;
#pragma unroll
    for (int i = 0; i < 8; ++i) {
        unsigned id = (bits >> (3 * i)) & 7u;
        // 3-level cndmask select tree over the 8 codebook entries
        float a0 = (id & 1) ? c0.y : c0.x;
        float a1 = (id & 1) ? c0.w : c0.z;
        float a2 = (id & 1) ? c1.y : c1.x;
        float a3 = (id & 1) ? c1.w : c1.z;
        float b0 = (id & 2) ? a1 : a0;
        float b1 = (id & 2) ? a3 : a2;
        float v  = (id & 4) ? b1 : b0;
        o[i] = f2bf_rne(v);
    }
    *(ushort8*)(W + ((size_t)g << 3)) = o;            // 16B coalesced store
}

// ---------------------------------------------------------------------------
// Kernel 2: x fp32 -> bf16. One thread per 8 elements.
// ---------------------------------------------------------------------------
__global__ __launch_bounds__(256) void k_cvt(const float* __restrict__ x,
                                             unsigned short* __restrict__ xb) {
    size_t t = (size_t)blockIdx.x * 256 + threadIdx.x;  // 0 .. 2097151
    const float4* xv = (const float4*)x;
    float4 a = xv[2 * t + 0];
    float4 b = xv[2 * t + 1];
    ushort8 o;
    o[0] = f2bf_rne(a.x); o[1] = f2bf_rne(a.y); o[2] = f2bf_rne(a.z); o[3] = f2bf_rne(a.w);
    o[4] = f2bf_rne(b.x); o[5] = f2bf_rne(b.y); o[6] = f2bf_rne(b.z); o[7] = f2bf_rne(b.w);
    ((ushort8*)xb)[t] = o;
}

// ---------------------------------------------------------------------------
// Kernel 3: bf16 GEMM  C[M,N] = A[M,K] * B[N,K]^T   (both K-major, m97-style)
// 128x128 block tile, BK=64, 256 threads = 4 waves in 2x2, each wave 64x64
// via 4x4 grid of mfma_f32_16x16x32_bf16. Staging via global_load_lds w=16.
// ---------------------------------------------------------------------------
__device__ __forceinline__ void gld16(const unsigned short* g, unsigned short* l) {
    __builtin_amdgcn_global_load_lds(
        (const __attribute__((address_space(1))) unsigned int*)g,
        (__attribute__((address_space(3))) unsigned int*)l, 16, 0, 0);
}

__global__ __launch_bounds__(256) void k_gemm(const unsigned short* __restrict__ A,
                                              const unsigned short* __restrict__ B,
                                              float* __restrict__ C) {
    __shared__ unsigned short As[BM * BK];   // 16 KB, row-major [m][k]
    __shared__ unsigned short Bs[BN * BK];   // 16 KB, row-major [n][k]

    const int tid  = threadIdx.x;
    const int lane = tid & 63;
    const int wave = tid >> 6;
    const int waveM = wave >> 1;             // 0..1
    const int waveN = wave & 1;              // 0..1
    const int bm = blockIdx.y * BM;
    const int bn = blockIdx.x * BN;

    // Staging map: call j covers rows [j*32, j*32+32) of the tile.
    // thread t -> tile row j*32 + t/8, k-offset (t&7)*8 (16B).
    // LDS dest = tile_base + j*4096B + t*16B  == wave-uniform base + lane*16. 
    const int srow = tid >> 3;               // 0..31
    const int scol = (tid & 7) * 8;          // 0,8,..,56
    const unsigned short* agp = A + (size_t)(bm + srow) * Kdim + scol;
    const unsigned short* bgp = B + (size_t)(bn + srow) * Kdim + scol;
    unsigned short* alp = &As[tid * 8];
    unsigned short* blp = &Bs[tid * 8];

    f32x4 acc[4][4];
    const f32x4 zero = {0.f, 0.f, 0.f, 0.f};
#pragma unroll
    for (int i = 0; i < 4; ++i)
#pragma unroll
        for (int j = 0; j < 4; ++j) acc[i][j] = zero;

    const int r15 = lane & 15;
    const int q   = lane >> 4;               // 0..3

    for (int kt = 0; kt < Kdim; kt += BK) {
#pragma unroll
        for (int j = 0; j < 4; ++j) {
            gld16(agp + (size_t)(j * 32) * Kdim + kt, alp + j * 2048);
            gld16(bgp + (size_t)(j * 32) * Kdim + kt, blp + j * 2048);
        }
        __syncthreads();   // compiler emits s_waitcnt vmcnt(0) before s_barrier

#pragma unroll
        for (int kk = 0; kk < 2; ++kk) {
            const int ko = kk * 32 + q * 8;
            bf16x8 af[4], bfr[4];
#pragma unroll
            for (int i = 0; i < 4; ++i)
                af[i] = *(const bf16x8*)(&As[(waveM * 64 + i * 16 + r15) * BK + ko]);
#pragma unroll
            for (int j = 0; j < 4; ++j)
                bfr[j] = *(const bf16x8*)(&Bs[(waveN * 64 + j * 16 + r15) * BK + ko]);
#pragma unroll
            for (int i = 0; i < 4; ++i)
#pragma unroll
                for (int j = 0; j < 4; ++j)
                    acc[i][j] = __builtin_amdgcn_mfma_f32_16x16x32_bf16(
                        af[i], bfr[j], acc[i][j], 0, 0, 0);
        }
        __syncthreads();
    }

    // Epilogue: C/D layout col = lane&15, row = (lane>>4)*4 + r  (m89/m91)
#pragma unroll
    for (int i = 0; i < 4; ++i) {
#pragma unroll
        for (int j = 0; j < 4; ++j) {
            int row = bm + waveM * 64 + i * 16 + q * 4;
            int col = bn + waveN * 64 + j * 16 + r15;
            float* outp = C + (size_t)row * Ndim + col;
#pragma unroll
            for (int r = 0; r < 4; ++r)
                outp[(size_t)r * Ndim] = acc[i][j][r];
        }
    }
}

// ---------------------------------------------------------------------------
extern "C" void kernel_launch(void* const* d_in, const int* in_sizes, int n_in,
                              void* d_out, int out_size, void* d_ws, size_t ws_size,
                              hipStream_t stream) {
    const float* x      = (const float*)d_in[0];   // 2048 x 8192 fp32
    const int*   packed = (const int*)d_in[1];     // 25165824 int32 (one byte each)
    const float* cb     = (const float*)d_in[2];   // 524288 x 8 fp32
    float* out = (float*)d_out;                    // 2048 x 8192 fp32

    unsigned short* Wb = (unsigned short*)d_ws;                          // 128 MB bf16 W
    unsigned short* Xb = (unsigned short*)d_ws + (size_t)Ndim * Kdim;    // 32 MB bf16 x

    // 1) dequantize W: 8388608 groups of 8 weights
    k_dequant<<<32768, 256, 0, stream>>>(packed, cb, Wb);
    // 2) convert x to bf16: 16777216 elements / 8 per thread
    k_cvt<<<8192, 256, 0, stream>>>(x, Xb);
    // 3) GEMM
    dim3 grid(Ndim / BN, Mdim / BM);   // (64, 16)
    k_gemm<<<grid, 256, 0, stream>>>(Xb, Wb, out);
}

// Round 2
// 529.035 us; speedup vs baseline: 1.1961x; 1.1961x over previous
//
#include <hip/hip_runtime.h>
#include <hip/hip_bf16.h>

// Problem constants
#define Mdim 2048
#define Ndim 8192
#define Kdim 8192
#define BM 128
#define BN 128
#define BK 64

typedef __bf16 bf16x8 __attribute__((ext_vector_type(8)));
typedef float f32x4 __attribute__((ext_vector_type(4)));
typedef unsigned short ushort8 __attribute__((ext_vector_type(8)));

__device__ __forceinline__ unsigned short f2bf_rne(float f) {
    unsigned u = __float_as_uint(f);
    u += 0x7fffu + ((u >> 16) & 1u);
    return (unsigned short)(u >> 16);
}

// ---------------------------------------------------------------------------
// Kernel 1: dequantize packed 3-bit indices -> bf16 W (Ndim x Kdim, K-major)
// Block handles 1024 groups (8192 weights). Packed bytes staged through LDS
// with fully-coalesced int4 loads; each thread decodes 4 strided groups
// (LDS read bank pattern 3t mod 32 -> 2-way, free).
// ---------------------------------------------------------------------------
#define DQG 1024
__global__ __launch_bounds__(256) void k_dequant(const int* __restrict__ packed,
                                                 const float* __restrict__ cb,
                                                 unsigned short* __restrict__ W) {
    __shared__ int sp[3 * DQG];                       // 12 KB
    const int t = threadIdx.x;
    const size_t gbase = (size_t)blockIdx.x * DQG;
    const int4* pv = (const int4*)(packed + gbase * 3);   // 768 int4 per block
    int4* sv = (int4*)sp;
    sv[t]       = pv[t];
    sv[t + 256] = pv[t + 256];
    sv[t + 512] = pv[t + 512];
    __syncthreads();
#pragma unroll
    for (int c = 0; c < 4; ++c) {
        const int g = t + 256 * c;                    // local group 0..1023
        int p0 = sp[3 * g + 0];
        int p1 = sp[3 * g + 1];
        int p2 = sp[3 * g + 2];
        unsigned bits = (unsigned)(p0 & 255) | ((unsigned)(p1 & 255) << 8) |
                        ((unsigned)(p2 & 255) << 16);
        const size_t gg = gbase + g;
        const float4* cv = (const float4*)(cb + ((gg >> 4) << 3));
        float4 c0 = cv[0];
        float4 c1 = cv[1];
        ushort8 o;
#pragma unroll
        for (int i = 0; i < 8; ++i) {
            unsigned id = (bits >> (3 * i)) & 7u;
            float a0 = (id & 1) ? c0.y : c0.x;
            float a1 = (id & 1) ? c0.w : c0.z;
            float a2 = (id & 1) ? c1.y : c1.x;
            float a3 = (id & 1) ? c1.w : c1.z;
            float b0 = (id & 2) ? a1 : a0;
            float b1 = (id & 2) ? a3 : a2;
            float v  = (id & 4) ? b1 : b0;
            o[i] = f2bf_rne(v);
        }
        *(ushort8*)(W + (gg << 3)) = o;               // 16B coalesced store
    }
}

// ---------------------------------------------------------------------------
// Kernel 2: x fp32 -> bf16. One thread per 8 elements.
// ---------------------------------------------------------------------------
__global__ __launch_bounds__(256) void k_cvt(const float* __restrict__ x,
                                             unsigned short* __restrict__ xb) {
    size_t t = (size_t)blockIdx.x * 256 + threadIdx.x;  // 0 .. 2097151
    const float4* xv = (const float4*)x;
    float4 a = xv[2 * t + 0];
    float4 b = xv[2 * t + 1];
    ushort8 o;
    o[0] = f2bf_rne(a.x); o[1] = f2bf_rne(a.y); o[2] = f2bf_rne(a.z); o[3] = f2bf_rne(a.w);
    o[4] = f2bf_rne(b.x); o[5] = f2bf_rne(b.y); o[6] = f2bf_rne(b.z); o[7] = f2bf_rne(b.w);
    ((ushort8*)xb)[t] = o;
}

// ---------------------------------------------------------------------------
// Kernel 3: bf16 GEMM  C[M,N] = A[M,K] * B[N,K]^T  (both K-major)
// 128x128 tile, BK=64, 4 waves (2x2), each 64x64 via 4x4 mfma 16x16x32.
// LDS layout XOR-swizzled at 16B-chunk granularity: row r's k-chunk kc lives
// at slot kc ^ (r&7). global_load_lds dest stays base+lane*16 (required);
// the swizzle is inverted on the per-lane GLOBAL source address instead.
// Fragment ds_read_b128: 16 lanes/q span all 32 banks 2-way (free, m136).
// ---------------------------------------------------------------------------
__device__ __forceinline__ void gld16(const unsigned short* g, unsigned short* l) {
    __builtin_amdgcn_global_load_lds(
        (const __attribute__((address_space(1))) unsigned int*)g,
        (__attribute__((address_space(3))) unsigned int*)l, 16, 0, 0);
}

__global__ __launch_bounds__(256) void k_gemm(const unsigned short* __restrict__ A,
                                              const unsigned short* __restrict__ B,
                                              float* __restrict__ C) {
    __shared__ unsigned short As[BM * BK];   // 16 KB
    __shared__ unsigned short Bs[BN * BK];   // 16 KB

    const int tid  = threadIdx.x;
    const int lane = tid & 63;
    const int wave = tid >> 6;
    const int waveM = wave >> 1;             // 0..1
    const int waveN = wave & 1;              // 0..1
    const int bm = blockIdx.y * BM;
    const int bn = blockIdx.x * BN;

    // Staging: call j covers tile rows [j*32, j*32+32). Thread t writes LDS
    // physical chunk j*256+t == (row = j*32 + t/8, slot = t&7); that slot
    // holds k-chunk (t&7) ^ (row&7) -> encode in the global source column.
    const int srow = tid >> 3;                               // 0..31
    const int scol = (((tid & 7) ^ ((tid >> 3) & 7))) * 8;   // swizzled k-chunk
    const unsigned short* agp = A + (size_t)(bm + srow) * Kdim + scol;
    const unsigned short* bgp = B + (size_t)(bn + srow) * Kdim + scol;
    unsigned short* alp = &As[tid * 8];
    unsigned short* blp = &Bs[tid * 8];

    f32x4 acc[4][4];
    const f32x4 zero = {0.f, 0.f, 0.f, 0.f};
#pragma unroll
    for (int i = 0; i < 4; ++i)
#pragma unroll
        for (int j = 0; j < 4; ++j) acc[i][j] = zero;

    const int r15 = lane & 15;
    const int q   = lane >> 4;               // 0..3
    const int rlo = r15 & 7;                 // row&7 for all fragment rows

    for (int kt = 0; kt < Kdim; kt += BK) {
#pragma unroll
        for (int j = 0; j < 4; ++j) {
            gld16(agp + (size_t)(j * 32) * Kdim + kt, alp + j * 2048);
            gld16(bgp + (size_t)(j * 32) * Kdim + kt, blp + j * 2048);
        }
        __syncthreads();

#pragma unroll
        for (int kk = 0; kk < 2; ++kk) {
            const int slot = ((kk * 4 + q) ^ rlo) * 8;   // swizzled LDS slot
            bf16x8 af[4], bfr[4];
#pragma unroll
            for (int i = 0; i < 4; ++i)
                af[i] = *(const bf16x8*)(&As[(waveM * 64 + i * 16 + r15) * BK + slot]);
#pragma unroll
            for (int j = 0; j < 4; ++j)
                bfr[j] = *(const bf16x8*)(&Bs[(waveN * 64 + j * 16 + r15) * BK + slot]);
#pragma unroll
            for (int i = 0; i < 4; ++i)
#pragma unroll
                for (int j = 0; j < 4; ++j)
                    acc[i][j] = __builtin_amdgcn_mfma_f32_16x16x32_bf16(
                        af[i], bfr[j], acc[i][j], 0, 0, 0);
        }
        __syncthreads();
    }

    // Epilogue: C/D layout col = lane&15, row = (lane>>4)*4 + r  (m89/m91)
#pragma unroll
    for (int i = 0; i < 4; ++i) {
#pragma unroll
        for (int j = 0; j < 4; ++j) {
            int row = bm + waveM * 64 + i * 16 + q * 4;
            int col = bn + waveN * 64 + j * 16 + r15;
            float* outp = C + (size_t)row * Ndim + col;
#pragma unroll
            for (int r = 0; r < 4; ++r)
                outp[(size_t)r * Ndim] = acc[i][j][r];
        }
    }
}

// ---------------------------------------------------------------------------
extern "C" void kernel_launch(void* const* d_in, const int* in_sizes, int n_in,
                              void* d_out, int out_size, void* d_ws, size_t ws_size,
                              hipStream_t stream) {
    const float* x      = (const float*)d_in[0];   // 2048 x 8192 fp32
    const int*   packed = (const int*)d_in[1];     // 25165824 int32 (one byte each)
    const float* cb     = (const float*)d_in[2];   // 524288 x 8 fp32
    float* out = (float*)d_out;                    // 2048 x 8192 fp32

    unsigned short* Wb = (unsigned short*)d_ws;                          // 128 MB bf16 W
    unsigned short* Xb = (unsigned short*)d_ws + (size_t)Ndim * Kdim;    // 32 MB bf16 x

    // 1) dequantize W: 8388608 groups / 1024 per block
    k_dequant<<<8192, 256, 0, stream>>>(packed, cb, Wb);
    // 2) convert x to bf16
    k_cvt<<<8192, 256, 0, stream>>>(x, Xb);
    // 3) GEMM
    dim3 grid(Ndim / BN, Mdim / BM);   // (64, 16)
    k_gemm<<<grid, 256, 0, stream>>>(Xb, Wb, out);
}